// Round 3
// baseline (2219.302 us; speedup 1.0000x reference)
//
#include <hip/hip_runtime.h>
#include <math.h>

#define TT 512
#define BB 256
#define DD 256
#define HH 256
#define QQ 256
#define MM (TT*BB)      // 131072 rows (t*B + b)
#define MTILE 16

// ---------------- prep: transpose W -> Bt[k][n] for k=0..511 (full K) ----------
// Bt[k][n] = W_g[q][k], n = g*256+q.  Rows 0..255 = x-half, 256..511 = conv-half.
__global__ __launch_bounds__(256)
void prep_bt_k(const float* __restrict__ Wf, const float* __restrict__ Wi,
               const float* __restrict__ Wu, const float* __restrict__ Wo,
               float* __restrict__ Bt)
{
    int idx = blockIdx.x * 256 + threadIdx.x;      // 512*1024 elements
    int k = idx >> 10, n = idx & 1023;
    int g = n >> 8, q = n & 255;
    const float* W = (g==0) ? Wf : (g==1) ? Wi : (g==2) ? Wu : Wo;
    Bt[idx] = W[q*512 + k];
}

__global__ __launch_bounds__(256)
void prep_wc_k(const float* __restrict__ Wf, const float* __restrict__ Wi,
               const float* __restrict__ Wu, const float* __restrict__ Wo,
               const float* __restrict__ bf, const float* __restrict__ bi,
               const float* __restrict__ bu, const float* __restrict__ bo,
               float* __restrict__ wcf, float* __restrict__ ball)
{
    int n = blockIdx.x * 256 + threadIdx.x;        // 1024
    int g = n >> 8, q = n & 255;
    const float* W    = (g==0) ? Wf : (g==1) ? Wi : (g==2) ? Wu : Wo;
    const float* bptr = (g==0) ? bf : (g==1) ? bi : (g==2) ? bu : bo;
    double s = 0.0;
    for (int j=0;j<256;j++) s += (double)W[q*512 + 256 + j];
    wcf[n] = (float)s; ball[n] = bptr[q];
}

// ---------------- main: conv + 4-gate GEMM + parity fraction + nonlinearity ----
__global__ __launch_bounds__(256)
void gates_k(const float* __restrict__ x, const float* __restrict__ Bt,
             const float* __restrict__ wcf, const float* __restrict__ ball,
             float* __restrict__ gates)
{
    __shared__ float As[MTILE][DD];     // 16 KiB x-tile
    __shared__ float convs[MTILE];
    const int tid = threadIdx.x;
    const int m0 = blockIdx.x * MTILE;

    // stage 16 rows of x (coalesced float4)
    const float4* xin = (const float4*)(x + (size_t)m0 * DD);
    float4* As4 = (float4*)&As[0][0];
    #pragma unroll
    for (int i=0;i<4;i++) As4[tid + 256*i] = xin[tid + 256*i];
    __syncthreads();

    // conv = parity fraction of (x > 0): wave 0 handles all 16 rows via ballot
    if (tid < 64) {
        for (int r=0;r<MTILE;r++){
            float4 v = *(const float4*)&As[r][tid*4];
            int b0 = v.x > 0.f, b1 = v.y > 0.f, b2 = v.z > 0.f, b3 = v.w > 0.f;
            int p1 = b0 ^ b1, p2 = p1 ^ b2, p3 = p2 ^ b3;
            int s = b0 + p1 + p2 + p3;                // sum of in-chunk prefix parities
            unsigned long long mask = __ballot(p3);   // chunk parities across lanes
            int X = (int)(__popcll(mask & ((1ull<<tid)-1ull)) & 1);
            int contrib = X ? 4 - s : s;
            #pragma unroll
            for (int off=1; off<64; off<<=1) contrib += __shfl_xor(contrib, off);
            if (tid==0) convs[r] = (float)contrib * (1.0f/DD);
        }
    }
    __syncthreads();

    // fp32 GEMM (x-half, k=0..255): 16 rows x 4 cols per thread, sequential-k
    float acc[MTILE][4];
    #pragma unroll
    for (int r=0;r<MTILE;r++){ acc[r][0]=0.f; acc[r][1]=0.f; acc[r][2]=0.f; acc[r][3]=0.f; }

    const float4* Btv = (const float4*)Bt;   // row k = 256 float4
    #pragma unroll 2
    for (int k4=0;k4<DD/4;k4++){
        float4 b0 = Btv[(4*k4+0)*256 + tid];
        float4 b1 = Btv[(4*k4+1)*256 + tid];
        float4 b2 = Btv[(4*k4+2)*256 + tid];
        float4 b3 = Btv[(4*k4+3)*256 + tid];
        #pragma unroll
        for (int r=0;r<MTILE;r++){
            float4 a = *(const float4*)&As[r][4*k4];
            acc[r][0] += a.x*b0.x; acc[r][1] += a.x*b0.y; acc[r][2] += a.x*b0.z; acc[r][3] += a.x*b0.w;
            acc[r][0] += a.y*b1.x; acc[r][1] += a.y*b1.y; acc[r][2] += a.y*b1.z; acc[r][3] += a.y*b1.w;
            acc[r][0] += a.z*b2.x; acc[r][1] += a.z*b2.y; acc[r][2] += a.z*b2.z; acc[r][3] += a.z*b2.w;
            acc[r][0] += a.w*b3.x; acc[r][1] += a.w*b3.y; acc[r][2] += a.w*b3.z; acc[r][3] += a.w*b3.w;
        }
    }

    // epilogue: threshold with exact sequential-f32-FMA-chain fixup near 0.5
    const int lane = tid & 63;
    const int wave = tid >> 6;                    // gate id: 0=f 1=i 2=u 3=o
    const unsigned long long ltmask = (1ull<<lane)-1ull;
    float4 wcv = ((const float4*)wcf)[tid];
    float4 bbv = ((const float4*)ball)[tid];
    float* gout = gates + (size_t)wave * MM;

    for (int r=0;r<MTILE;r++){
        float conv = convs[r];
        int bit[4];
        #pragma unroll
        for (int j=0;j<4;j++){
            float wcj = (j==0)?wcv.x:(j==1)?wcv.y:(j==2)?wcv.z:wcv.w;
            float bj  = (j==0)?bbv.x:(j==1)?bbv.y:(j==2)?bbv.z:bbv.w;
            float rf = fmaf(conv, wcj, acc[r][j]) + bj;
            if (__builtin_expect(fabsf(rf - 0.5f) < 1e-3f, 0)) {
                // near-threshold: emulate the CPU BLAS per-element order exactly:
                // single f32 accumulator, sequential k=0..511, FMA each step,
                // conv-part as 256 individual FMAs, bias added last.
                int n = tid*4 + j;
                float a2 = 0.f;
                for (int k=0;k<DD;k++)
                    a2 = fmaf(As[r][k], Bt[k*1024 + n], a2);
                for (int k=DD;k<2*DD;k++)
                    a2 = fmaf(conv, Bt[k*1024 + n], a2);
                float rawf = __fadd_rn(a2, bj);
                bit[j] = rawf > 0.5f;
            } else {
                bit[j] = rf > 0.5f;
            }
        }
        int p1 = bit[0]^bit[1], p2 = p1^bit[2], p3 = p2^bit[3];
        int s = bit[0] + p1 + p2 + p3;
        unsigned long long mask = __ballot(p3);
        int X = (int)(__popcll(mask & ltmask) & 1);
        int contrib = X ? 4 - s : s;
        #pragma unroll
        for (int off=1; off<64; off<<=1) contrib += __shfl_xor(contrib, off);
        if (lane==0){
            float pf = (float)contrib * (1.0f/QQ);
            float val = (wave==2) ? tanhf(pf) : 1.0f/(1.0f + expf(-pf));
            gout[m0 + r] = val;
        }
    }
}

// ---------------- scan + broadcast write ----------------
__global__ __launch_bounds__(256)
void scan_k(const float* __restrict__ gates, const float* __restrict__ cx0,
            float* __restrict__ out)
{
    const int b = blockIdx.x;
    const int s = blockIdx.y;      // t-stripe (8 stripes of 64)
    const int h = threadIdx.x;
    const float* F = gates;
    const float* I = gates + MM;
    const float* G = gates + 2*(size_t)MM;
    const float* O = gates + 3*(size_t)MM;
    float c = cx0[b*HH + h];
    float hv = 0.f;
    const int t0 = s*64, t1 = t0+64;
    for (int t=0;t<t1;t++){
        int m = t*BB + b;
        float f=F[m], i=I[m], g=G[m];
        // mirror numpy elementwise rounding: separate mul/mul/add, no contraction
        float u1 = __fmul_rn(f, c);
        float u2 = __fmul_rn(i, g);
        c = __fadd_rn(u1, u2);
        if (t >= t0){
            float o=O[m];
            hv = __fmul_rn(o, tanhf(c));
            out[(size_t)m * HH + h] = hv;
        }
    }
    if (s == 7){
        size_t base = (size_t)TT*BB*HH;
        out[base + (size_t)b*HH + h] = hv;               // hx
        out[base + (size_t)BB*HH + (size_t)b*HH + h] = c; // cx
    }
}

extern "C" void kernel_launch(void* const* d_in, const int* in_sizes, int n_in,
                              void* d_out, int out_size, void* d_ws, size_t ws_size,
                              hipStream_t stream)
{
    const float* x   = (const float*)d_in[0];
    const float* cx0 = (const float*)d_in[2];
    const float* Wf  = (const float*)d_in[3];
    const float* bf  = (const float*)d_in[4];
    const float* Wi  = (const float*)d_in[5];
    const float* bi  = (const float*)d_in[6];
    const float* Wu  = (const float*)d_in[7];
    const float* bu  = (const float*)d_in[8];
    const float* Wo  = (const float*)d_in[9];
    const float* bo  = (const float*)d_in[10];

    char* ws = (char*)d_ws;
    float*  Bt    = (float*) (ws);                         // 512*1024*4 = 2 MiB
    float*  wcf   = (float*) (ws + (2ul<<20));             // 4 KiB
    float*  ball  = (float*) (ws + (2ul<<20) + 4096);      // 4 KiB
    float*  gates = (float*) (ws + (2ul<<20) + 16384);     // 4*MM*4 = 2 MiB
    float*  out   = (float*)d_out;

    hipLaunchKernelGGL(prep_bt_k, dim3(2048), dim3(256), 0, stream, Wf, Wi, Wu, Wo, Bt);
    hipLaunchKernelGGL(prep_wc_k, dim3(4),    dim3(256), 0, stream, Wf, Wi, Wu, Wo,
                       bf, bi, bu, bo, wcf, ball);
    hipLaunchKernelGGL(gates_k,   dim3(MM/MTILE), dim3(256), 0, stream,
                       x, Bt, wcf, ball, gates);
    hipLaunchKernelGGL(scan_k,    dim3(BB, 8), dim3(256), 0, stream, gates, cx0, out);
}

// Round 5
// 1700.702 us; speedup vs baseline: 1.3049x; 1.3049x over previous
//
#include <hip/hip_runtime.h>
#include <math.h>

#define TT 512
#define BB 256
#define DD 256
#define HH 256
#define QQ 256
#define MM (TT*BB)      // 131072 rows (t*B + b)
#define MTILE 16
#define WND 1e-3f

// ---------------- prep: transpose W -> Bt[k][n] for k=0..511 (full K) ----------
// Bt[k][n] = W_g[q][k], n = g*256+q.  Rows 0..255 = x-half, 256..511 = conv-half.
__global__ __launch_bounds__(256)
void prep_bt_k(const float* __restrict__ Wf, const float* __restrict__ Wi,
               const float* __restrict__ Wu, const float* __restrict__ Wo,
               float* __restrict__ Bt)
{
    int idx = blockIdx.x * 256 + threadIdx.x;      // 512*1024 elements
    int k = idx >> 10, n = idx & 1023;
    int g = n >> 8, q = n & 255;
    const float* W = (g==0) ? Wf : (g==1) ? Wi : (g==2) ? Wu : Wo;
    Bt[idx] = W[q*512 + k];
}

__global__ __launch_bounds__(256)
void prep_wc_k(const float* __restrict__ Wf, const float* __restrict__ Wi,
               const float* __restrict__ Wu, const float* __restrict__ Wo,
               const float* __restrict__ bf, const float* __restrict__ bi,
               const float* __restrict__ bu, const float* __restrict__ bo,
               float* __restrict__ wcf, float* __restrict__ ball)
{
    int n = blockIdx.x * 256 + threadIdx.x;        // 1024
    int g = n >> 8, q = n & 255;
    const float* W    = (g==0) ? Wf : (g==1) ? Wi : (g==2) ? Wu : Wo;
    const float* bptr = (g==0) ? bf : (g==1) ? bi : (g==2) ? bu : bo;
    double s = 0.0;
    for (int j=0;j<256;j++) s += (double)W[q*512 + 256 + j];
    wcf[n] = (float)s; ball[n] = bptr[q];
}

// exact emulation of the CPU per-element sequential f32 FMA chain (bias last)
__device__ __forceinline__ int chain_bit(const float* __restrict__ Arow,
                                         const float* __restrict__ Bt,
                                         int n, float conv, float bj)
{
    float a2 = 0.f;
    for (int k=0;k<DD;k++)  a2 = fmaf(Arow[k], Bt[k*1024 + n], a2);
    for (int k=0;k<DD;k++)  a2 = fmaf(conv,    Bt[(DD+k)*1024 + n], a2);
    return __fadd_rn(a2, bj) > 0.5f;
}

// ---------------- main: conv + 4-gate GEMM + parity fraction + nonlinearity ----
__global__ __launch_bounds__(256, 3)
void gates_k(const float* __restrict__ x, const float* __restrict__ Bt,
             const float* __restrict__ wcf, const float* __restrict__ ball,
             float* __restrict__ gates)
{
    __shared__ float As[MTILE][DD];     // 16 KiB x-tile
    __shared__ float convs[MTILE];
    const int tid  = threadIdx.x;
    const int lane = tid & 63;
    const int wave = tid >> 6;                    // gate id: 0=f 1=i 2=u 3=o
    const int m0 = blockIdx.x * MTILE;

    // stage 16 rows of x (coalesced float4)
    const float4* xin = (const float4*)(x + (size_t)m0 * DD);
    float4* As4 = (float4*)&As[0][0];
    #pragma unroll
    for (int i=0;i<4;i++) As4[tid + 256*i] = xin[tid + 256*i];
    __syncthreads();

    // conv = parity fraction of (x > 0): wave w handles rows 4w..4w+3
    {
        const unsigned long long ltm = (1ull<<lane)-1ull;
        for (int r = 4*wave; r < 4*wave+4; r++){
            float4 v = *(const float4*)&As[r][lane*4];
            int b0 = v.x > 0.f, b1 = v.y > 0.f, b2 = v.z > 0.f, b3 = v.w > 0.f;
            int p1 = b0 ^ b1, p2 = p1 ^ b2, p3 = p2 ^ b3;
            int s = b0 + p1 + p2 + p3;                // sum of in-chunk prefix parities
            unsigned long long mask = __ballot(p3);   // chunk parities across lanes
            int X = (int)(__popcll(mask & ltm) & 1);
            int contrib = X ? 4 - s : s;
            #pragma unroll
            for (int off=1; off<64; off<<=1) contrib += __shfl_xor(contrib, off);
            if (lane==0) convs[r] = (float)contrib * (1.0f/DD);
        }
    }
    __syncthreads();

    // fp32 GEMM (x-half, k=0..255): 16 rows x 4 cols per thread
    // acc MUST stay static-indexed everywhere -> registers (rule #20)
    float4 acc[MTILE];
    #pragma unroll
    for (int r=0;r<MTILE;r++) acc[r] = make_float4(0.f,0.f,0.f,0.f);

    const float4* Btv = (const float4*)Bt;   // row k = 256 float4
    #pragma unroll 2
    for (int k4=0;k4<DD/4;k4++){
        float4 b0 = Btv[(4*k4+0)*256 + tid];
        float4 b1 = Btv[(4*k4+1)*256 + tid];
        float4 b2 = Btv[(4*k4+2)*256 + tid];
        float4 b3 = Btv[(4*k4+3)*256 + tid];
        #pragma unroll
        for (int r=0;r<MTILE;r++){
            float4 a = *(const float4*)&As[r][4*k4];
            acc[r].x += a.x*b0.x; acc[r].y += a.x*b0.y; acc[r].z += a.x*b0.z; acc[r].w += a.x*b0.w;
            acc[r].x += a.y*b1.x; acc[r].y += a.y*b1.y; acc[r].z += a.y*b1.z; acc[r].w += a.y*b1.w;
            acc[r].x += a.z*b2.x; acc[r].y += a.z*b2.y; acc[r].z += a.z*b2.z; acc[r].w += a.z*b2.w;
            acc[r].x += a.w*b3.x; acc[r].y += a.w*b3.y; acc[r].z += a.w*b3.z; acc[r].w += a.w*b3.w;
        }
    }

    // epilogue: threshold with exact f32-chain fixup near 0.5, parity via ballot
    const unsigned long long ltmask = (1ull<<lane)-1ull;
    float4 wcv = ((const float4*)wcf)[tid];
    float4 bbv = ((const float4*)ball)[tid];
    float* gout = gates + (size_t)wave * MM;

    #pragma unroll
    for (int r=0;r<MTILE;r++){
        float conv = convs[r];
        float r0 = fmaf(conv, wcv.x, acc[r].x) + bbv.x;
        float r1 = fmaf(conv, wcv.y, acc[r].y) + bbv.y;
        float r2 = fmaf(conv, wcv.z, acc[r].z) + bbv.z;
        float r3 = fmaf(conv, wcv.w, acc[r].w) + bbv.w;
        int b0 = __builtin_expect(fabsf(r0-0.5f) < WND, 0) ? chain_bit(As[r], Bt, tid*4+0, conv, bbv.x) : (r0 > 0.5f);
        int b1 = __builtin_expect(fabsf(r1-0.5f) < WND, 0) ? chain_bit(As[r], Bt, tid*4+1, conv, bbv.y) : (r1 > 0.5f);
        int b2 = __builtin_expect(fabsf(r2-0.5f) < WND, 0) ? chain_bit(As[r], Bt, tid*4+2, conv, bbv.z) : (r2 > 0.5f);
        int b3 = __builtin_expect(fabsf(r3-0.5f) < WND, 0) ? chain_bit(As[r], Bt, tid*4+3, conv, bbv.w) : (r3 > 0.5f);
        int p1 = b0^b1, p2 = p1^b2, p3 = p2^b3;
        int s = b0 + p1 + p2 + p3;
        unsigned long long mask = __ballot(p3);
        int X = (int)(__popcll(mask & ltmask) & 1);
        int contrib = X ? 4 - s : s;
        #pragma unroll
        for (int off=1; off<64; off<<=1) contrib += __shfl_xor(contrib, off);
        if (lane==0){
            float pf = (float)contrib * (1.0f/QQ);
            float val = (wave==2) ? tanhf(pf) : 1.0f/(1.0f + expf(-pf));
            gout[m0 + r] = val;
        }
    }
}

// ---------------- linear-recurrence scan: P_t = prod f, S_t = c_t given c0=0 ----
__global__ __launch_bounds__(64)
void scan1_k(const float* __restrict__ gates, float* __restrict__ P,
             float* __restrict__ S)
{
    int b = blockIdx.x * 64 + threadIdx.x;     // 256 lanes total
    const float* F = gates;
    const float* I = gates + MM;
    const float* G = gates + 2*(size_t)MM;
    float p = 1.f, s = 0.f;
    #pragma unroll 4
    for (int t=0;t<TT;t++){
        int m = t*BB + b;
        float f=F[m], i=I[m], g=G[m];
        // bit-identical to reference per-step rounding: mul, mul, add
        s = __fadd_rn(__fmul_rn(f, s), __fmul_rn(i, g));
        p = __fmul_rn(p, f);
        P[m] = p; S[m] = s;
    }
}

// ---------------- broadcast: c = P*c0 + S (== S when c0==0), h = o*tanh(c) ------
__global__ __launch_bounds__(256)
void out_k(const float* __restrict__ gates, const float* __restrict__ P,
           const float* __restrict__ S, const float* __restrict__ cx0,
           float* __restrict__ out)
{
    int idx = blockIdx.x * 256 + threadIdx.x;   // one float4 of h per thread
    int m  = idx >> 6;                          // wave-uniform row
    int h4 = (idx & 63) * 4;
    int b  = m & (BB-1);
    const float* O = gates + 3*(size_t)MM;
    float p = P[m], s = S[m], o = O[m];
    float4 c0 = *(const float4*)&cx0[b*HH + h4];
    float4 c, hv;
    c.x = __fadd_rn(__fmul_rn(p, c0.x), s);
    c.y = __fadd_rn(__fmul_rn(p, c0.y), s);
    c.z = __fadd_rn(__fmul_rn(p, c0.z), s);
    c.w = __fadd_rn(__fmul_rn(p, c0.w), s);
    hv.x = __fmul_rn(o, tanhf(c.x));
    hv.y = __fmul_rn(o, tanhf(c.y));
    hv.z = __fmul_rn(o, tanhf(c.z));
    hv.w = __fmul_rn(o, tanhf(c.w));
    *(float4*)&out[(size_t)m * HH + h4] = hv;
    if (m >= (TT-1)*BB){                        // t == T-1: also emit hx, cx
        size_t base = (size_t)TT*BB*HH;
        *(float4*)&out[base + (size_t)b*HH + h4] = hv;
        *(float4*)&out[base + (size_t)BB*HH + (size_t)b*HH + h4] = c;
    }
}

extern "C" void kernel_launch(void* const* d_in, const int* in_sizes, int n_in,
                              void* d_out, int out_size, void* d_ws, size_t ws_size,
                              hipStream_t stream)
{
    const float* x   = (const float*)d_in[0];
    const float* cx0 = (const float*)d_in[2];
    const float* Wf  = (const float*)d_in[3];
    const float* bf  = (const float*)d_in[4];
    const float* Wi  = (const float*)d_in[5];
    const float* bi  = (const float*)d_in[6];
    const float* Wu  = (const float*)d_in[7];
    const float* bu  = (const float*)d_in[8];
    const float* Wo  = (const float*)d_in[9];
    const float* bo  = (const float*)d_in[10];

    char* ws = (char*)d_ws;
    float* Bt    = (float*)(ws);                           // 512*1024*4 = 2 MiB
    float* wcf   = (float*)(ws + (2ul<<20));               // 4 KiB
    float* ball  = (float*)(ws + (2ul<<20) + 4096);        // 4 KiB
    float* gates = (float*)(ws + (2ul<<20) + 16384);       // 4*MM*4 = 2 MiB
    float* Pbuf  = (float*)(ws + (4ul<<20) + 16384);       // MM*4 = 512 KiB
    float* Sbuf  = (float*)(ws + (4ul<<20) + 16384 + (MM*4)); // 512 KiB
    float* out   = (float*)d_out;

    hipLaunchKernelGGL(prep_bt_k, dim3(2048), dim3(256), 0, stream, Wf, Wi, Wu, Wo, Bt);
    hipLaunchKernelGGL(prep_wc_k, dim3(4),    dim3(256), 0, stream, Wf, Wi, Wu, Wo,
                       bf, bi, bu, bo, wcf, ball);
    hipLaunchKernelGGL(gates_k,   dim3(MM/MTILE), dim3(256), 0, stream,
                       x, Bt, wcf, ball, gates);
    hipLaunchKernelGGL(scan1_k,   dim3(4),  dim3(64),  0, stream, gates, Pbuf, Sbuf);
    hipLaunchKernelGGL(out_k,     dim3((MM*HH/4)/256), dim3(256), 0, stream,
                       gates, Pbuf, Sbuf, cx0, out);
}

// Round 7
// 1016.171 us; speedup vs baseline: 2.1840x; 1.6736x over previous
//
#include <hip/hip_runtime.h>
#include <math.h>

#define TT 512
#define BB 256
#define DD 256
#define HH 256
#define QQ 256
#define MM (TT*BB)      // 131072 rows (t*B + b)
#define MTILE 16
#define WND 4e-4f
#define QCAP (1u<<19)   // 524288 queue items (10x expected)

typedef float  f32x4  __attribute__((ext_vector_type(4)));
typedef short  bf16x8 __attribute__((ext_vector_type(8)));

__device__ __forceinline__ unsigned short bf16rn(float x){
    unsigned int u = __float_as_uint(x);
    unsigned int r = u + 0x7FFFu + ((u>>16)&1u);
    return (unsigned short)(r>>16);
}
__device__ __forceinline__ float bf2f(unsigned short h){
    return __uint_as_float(((unsigned int)h)<<16);
}

// ---- prep: per-n f32(conv-column-sum) and bias -------------------------------
__global__ __launch_bounds__(256)
void prep_wc_k(const float* __restrict__ Wf, const float* __restrict__ Wi,
               const float* __restrict__ Wu, const float* __restrict__ Wo,
               const float* __restrict__ bf, const float* __restrict__ bi,
               const float* __restrict__ bu, const float* __restrict__ bo,
               float* __restrict__ wcf, float* __restrict__ ball)
{
    int n = blockIdx.x * 256 + threadIdx.x;        // 1024
    int g = n >> 8, q = n & 255;
    const float* W    = (g==0) ? Wf : (g==1) ? Wi : (g==2) ? Wu : Wo;
    const float* bptr = (g==0) ? bf : (g==1) ? bi : (g==2) ? bu : bo;
    double s = 0.0;
    for (int j=0;j<256;j++) s += (double)W[q*512 + 256 + j];
    wcf[n] = (float)s; ball[n] = bptr[q];
}

// ---- prep: W -> bf16 hi/lo MFMA B-fragments ----------------------------------
// B-frag layout for 16x16x32: lane holds col=lane&15, k = kt*32 + (lane>>4)*8 + j.
// Flat index [kt][nt_global][lane] * 8 bf16.
__global__ __launch_bounds__(256)
void prep_bfrag_k(const float* __restrict__ Wf, const float* __restrict__ Wi,
                  const float* __restrict__ Wu, const float* __restrict__ Wo,
                  unsigned short* __restrict__ Bhi, unsigned short* __restrict__ Blo)
{
    int tau = blockIdx.x*256 + threadIdx.x;        // 32768 = 8kt * 64nt * 64lane
    int kt = tau >> 12, rest = tau & 4095;
    int nt = rest >> 6, lane = rest & 63;
    int col = nt*16 + (lane & 15);
    int g = col >> 8, q = col & 255;
    const float* W = (g==0) ? Wf : (g==1) ? Wi : (g==2) ? Wu : Wo;
    int k0 = kt*32 + (lane>>4)*8;
    unsigned int hp[4], lp[4];
    #pragma unroll
    for (int jj=0;jj<4;jj++){
        float w0 = W[q*512 + k0 + 2*jj];
        float w1 = W[q*512 + k0 + 2*jj + 1];
        unsigned short h0 = bf16rn(w0), h1 = bf16rn(w1);
        unsigned short l0 = bf16rn(w0 - bf2f(h0)), l1 = bf16rn(w1 - bf2f(h1));
        hp[jj] = (unsigned int)h0 | ((unsigned int)h1 << 16);
        lp[jj] = (unsigned int)l0 | ((unsigned int)l1 << 16);
    }
    *(uint4*)(Bhi + (size_t)tau*8) = make_uint4(hp[0],hp[1],hp[2],hp[3]);
    *(uint4*)(Blo + (size_t)tau*8) = make_uint4(lp[0],lp[1],lp[2],lp[3]);
}

// ---- main: conv + 3-product bf16-split MFMA + provisional bits + queue -------
__global__ __launch_bounds__(256, 3)
void gates_k(const float* __restrict__ x,
             const unsigned short* __restrict__ Bhi, const unsigned short* __restrict__ Blo,
             const float* __restrict__ wcf, const float* __restrict__ ball,
             float* __restrict__ convbuf,
             unsigned long long* __restrict__ bits,
             unsigned int* __restrict__ qctr, unsigned int* __restrict__ qbuf)
{
    __shared__ unsigned short Ahi[MTILE*DD];   // 8 KB, XOR-swizzled rows
    __shared__ unsigned short Alo[MTILE*DD];   // 8 KB
    __shared__ float convs[MTILE];
    const int tid = threadIdx.x;
    const int l   = tid & 63;
    const int w   = tid >> 6;                  // wave = gate id (0=f 1=i 2=u 3=o)
    const int m0  = blockIdx.x * MTILE;
    const unsigned long long ltm = (1ull<<l)-1ull;

    // stage x -> bf16 hi/lo LDS (+ conv per row); wave w loads rows w,4+w,8+w,12+w
    const float4* xin = (const float4*)(x + (size_t)m0 * DD);
    #pragma unroll
    for (int i=0;i<4;i++){
        int row = 4*i + w;
        float4 v = xin[256*i + tid];
        // conv parity bits
        int b0=v.x>0.f, b1=v.y>0.f, b2=v.z>0.f, b3=v.w>0.f;
        int p1=b0^b1, p2=p1^b2, p3=p2^b3;
        int s=b0+p1+p2+p3;
        unsigned long long mask=__ballot(p3);
        int X=(int)(__popcll(mask&ltm)&1);
        int contrib = X ? 4-s : s;
        #pragma unroll
        for(int off=1;off<64;off<<=1) contrib += __shfl_xor(contrib,off);
        if (l==0){ float cv=(float)contrib*(1.0f/DD); convs[row]=cv; convbuf[m0+row]=cv; }
        // bf16 RN split, pack 4 elems = 8B per plane
        unsigned short h0=bf16rn(v.x), h1=bf16rn(v.y), h2=bf16rn(v.z), h3=bf16rn(v.w);
        unsigned short q0=bf16rn(v.x-bf2f(h0)), q1=bf16rn(v.y-bf2f(h1));
        unsigned short q2=bf16rn(v.z-bf2f(h2)), q3=bf16rn(v.w-bf2f(h3));
        uint2 hi2 = make_uint2((unsigned)h0|((unsigned)h1<<16), (unsigned)h2|((unsigned)h3<<16));
        uint2 lo2 = make_uint2((unsigned)q0|((unsigned)q1<<16), (unsigned)q2|((unsigned)q3<<16));
        int baddr = (row*512 + l*8) ^ ((row&7)<<4);
        *(uint2*)((char*)Ahi + baddr) = hi2;
        *(uint2*)((char*)Alo + baddr) = lo2;
    }
    __syncthreads();

    // MFMA: per wave 16 rows x 256 cols (gate w), K=256, 3 products
    f32x4 acc[16];
    #pragma unroll
    for (int t=0;t<16;t++) acc[t] = (f32x4){0.f,0.f,0.f,0.f};

    const int arow = l & 15;
    const int abase = arow*512 + (l>>4)*16;
    const int aswz = (arow&7)<<4;

    #pragma unroll
    for (int kt=0; kt<8; kt++){
        int aaddr = (abase + kt*64) ^ aswz;
        bf16x8 ah = *(const bf16x8*)((const char*)Ahi + aaddr);
        bf16x8 al = *(const bf16x8*)((const char*)Alo + aaddr);
        const unsigned short* bh = Bhi + ((size_t)(kt*64 + 16*w)*64 + l)*8;
        const unsigned short* bl = Blo + ((size_t)(kt*64 + 16*w)*64 + l)*8;
        #pragma unroll
        for (int t=0;t<16;t++){
            bf16x8 vbh = *(const bf16x8*)(bh + (size_t)t*512);
            bf16x8 vbl = *(const bf16x8*)(bl + (size_t)t*512);
            acc[t] = __builtin_amdgcn_mfma_f32_16x16x32_bf16(ah, vbh, acc[t], 0,0,0);
            acc[t] = __builtin_amdgcn_mfma_f32_16x16x32_bf16(ah, vbl, acc[t], 0,0,0);
            acc[t] = __builtin_amdgcn_mfma_f32_16x16x32_bf16(al, vbh, acc[t], 0,0,0);
        }
    }

    // epilogue: raw -> provisional bit; assemble packed bit-words; queue ambiguous
    const int myu = l>>4, myj = l&3, mygrp = (l&15)>>2;
    float cva = convs[myu*4+0], cvb = convs[myu*4+1];
    float cvc = convs[myu*4+2], cvd = convs[myu*4+3];
    unsigned long long word = 0;
    #pragma unroll
    for (int t=0;t<16;t++){
        int n = w*256 + t*16 + (l&15);
        float wc = wcf[n], bb = ball[n];
        #pragma unroll
        for (int j=0;j<4;j++){
            float cj = (j==0)?cva:(j==1)?cvb:(j==2)?cvc:cvd;
            float rf = __fadd_rn(__fmaf_rn(cj, wc, acc[t][j]), bb);
            int bit = rf > 0.5f;
            unsigned long long B = __ballot(bit != 0);
            int cond = (j==myj) & ((t>>2)==myu);
            unsigned long long chunk = (B >> (mygrp*16)) & 0xFFFFull;
            word |= cond ? (chunk << ((t&3)*16)) : 0ull;
            bool win = fabsf(rf - 0.5f) < WND;
            unsigned long long wm = __ballot(win);
            if (wm){
                int leader = (int)__ffsll(wm) - 1;
                unsigned int cnt = (unsigned int)__popcll(wm);
                unsigned int base = 0;
                if (l == leader) base = atomicAdd(qctr, cnt);
                base = (unsigned int)__shfl((int)base, leader);
                if (win){
                    unsigned int pos = base + (unsigned int)__popcll(wm & ltm);
                    if (pos < QCAP){
                        unsigned int mrow = (unsigned int)(m0 + myu*4 + j);
                        qbuf[pos] = mrow | ((unsigned int)w<<17)
                                  | ((unsigned int)(t*16 + (l&15))<<19)
                                  | ((unsigned int)bit<<27);
                    }
                }
            }
        }
    }
    bits[((size_t)(m0 + arow)*4 + w)*4 + myu] = word;
}

// ---- fixup: exact sequential-f32-FMA chain per queue item, patch bits --------
__global__ __launch_bounds__(256)
void fixup_k(const float* __restrict__ x,
             const float* __restrict__ Wf, const float* __restrict__ Wi,
             const float* __restrict__ Wu, const float* __restrict__ Wo,
             const float* __restrict__ ball, const float* __restrict__ convbuf,
             const unsigned int* __restrict__ qctr, const unsigned int* __restrict__ qbuf,
             unsigned long long* __restrict__ bits)
{
    unsigned int cnt = *qctr; if (cnt > QCAP) cnt = QCAP;
    unsigned int stride = gridDim.x * blockDim.x;
    for (unsigned int i = blockIdx.x*blockDim.x + threadIdx.x; i < cnt; i += stride){
        unsigned int it = qbuf[i];
        int m = it & 0x1FFFF;
        int g = (it>>17)&3;
        int q = (it>>19)&255;
        int prov = (it>>27)&1;
        const float* W = (g==0)?Wf:(g==1)?Wi:(g==2)?Wu:Wo;
        const float* wr = W + (size_t)q*512;
        const float* xr = x + (size_t)m*DD;
        float cv = convbuf[m];
        float a = 0.f;
        for (int k=0;k<DD;k++) a = __fmaf_rn(xr[k], wr[k], a);
        for (int k=0;k<DD;k++) a = __fmaf_rn(cv, wr[DD+k], a);
        float raw = __fadd_rn(a, ball[g*256+q]);
        int bit = raw > 0.5f;
        if (bit != prov)
            atomicXor(&bits[((size_t)m*4 + g)*4 + (q>>6)], 1ull<<(q&63));
    }
}

// ---- finalize: packed bits -> parity fraction -> gate value ------------------
__global__ __launch_bounds__(256)
void finalize_k(const unsigned long long* __restrict__ bits, float* __restrict__ gates)
{
    const int l = threadIdx.x & 63;
    const int wid = (int)((blockIdx.x*256 + threadIdx.x) >> 6);  // 16384 waves
    const unsigned long long ltm = (1ull<<l)-1ull;
    for (int it=0; it<32; it++){
        int R = wid*32 + it;                       // (m,gate) row, 0..524287
        unsigned long long wbits = bits[(size_t)R*4 + (l>>4)];
        int nib = (int)((wbits >> ((l&15)*4)) & 0xF);
        int b0=nib&1, b1=(nib>>1)&1, b2=(nib>>2)&1, b3=(nib>>3)&1;
        int p1=b0^b1, p2=p1^b2, p3=p2^b3;
        int s=b0+p1+p2+p3;
        unsigned long long mask=__ballot(p3);
        int X=(int)(__popcll(mask&ltm)&1);
        int contrib = X ? 4-s : s;
        #pragma unroll
        for(int off=1;off<64;off<<=1) contrib += __shfl_xor(contrib,off);
        if (l==0){
            int m = R>>2, g = R&3;
            float pf = (float)contrib*(1.0f/QQ);
            float val = (g==2) ? tanhf(pf) : 1.0f/(1.0f+expf(-pf));
            gates[(size_t)g*MM + m] = val;
        }
    }
}

// ---- linear-recurrence scan: P_t = prod f, S_t = c_t given c0=0 --------------
__global__ __launch_bounds__(64)
void scan1_k(const float* __restrict__ gates, float* __restrict__ P,
             float* __restrict__ S)
{
    int b = blockIdx.x * 64 + threadIdx.x;     // 256 lanes total
    const float* F = gates;
    const float* I = gates + MM;
    const float* G = gates + 2*(size_t)MM;
    float p = 1.f, s = 0.f;
    #pragma unroll 4
    for (int t=0;t<TT;t++){
        int m = t*BB + b;
        float f=F[m], i=I[m], g=G[m];
        s = __fadd_rn(__fmul_rn(f, s), __fmul_rn(i, g));
        p = __fmul_rn(p, f);
        P[m] = p; S[m] = s;
    }
}

// ---- broadcast: c = P*c0 + S, h = o*tanh(c) ----------------------------------
__global__ __launch_bounds__(256)
void out_k(const float* __restrict__ gates, const float* __restrict__ P,
           const float* __restrict__ S, const float* __restrict__ cx0,
           float* __restrict__ out)
{
    int idx = blockIdx.x * 256 + threadIdx.x;   // one float4 of h per thread
    int m  = idx >> 6;                          // wave-uniform row
    int h4 = (idx & 63) * 4;
    int b  = m & (BB-1);
    const float* O = gates + 3*(size_t)MM;
    float p = P[m], s = S[m], o = O[m];
    float4 c0 = *(const float4*)&cx0[b*HH + h4];
    float4 c, hv;
    c.x = __fadd_rn(__fmul_rn(p, c0.x), s);
    c.y = __fadd_rn(__fmul_rn(p, c0.y), s);
    c.z = __fadd_rn(__fmul_rn(p, c0.z), s);
    c.w = __fadd_rn(__fmul_rn(p, c0.w), s);
    hv.x = __fmul_rn(o, tanhf(c.x));
    hv.y = __fmul_rn(o, tanhf(c.y));
    hv.z = __fmul_rn(o, tanhf(c.z));
    hv.w = __fmul_rn(o, tanhf(c.w));
    *(float4*)&out[(size_t)m * HH + h4] = hv;
    if (m >= (TT-1)*BB){                        // t == T-1: also emit hx, cx
        size_t base = (size_t)TT*BB*HH;
        *(float4*)&out[base + (size_t)b*HH + h4] = hv;
        *(float4*)&out[base + (size_t)BB*HH + (size_t)b*HH + h4] = c;
    }
}

extern "C" void kernel_launch(void* const* d_in, const int* in_sizes, int n_in,
                              void* d_out, int out_size, void* d_ws, size_t ws_size,
                              hipStream_t stream)
{
    const float* x   = (const float*)d_in[0];
    const float* cx0 = (const float*)d_in[2];
    const float* Wf  = (const float*)d_in[3];
    const float* bf  = (const float*)d_in[4];
    const float* Wi  = (const float*)d_in[5];
    const float* bi  = (const float*)d_in[6];
    const float* Wu  = (const float*)d_in[7];
    const float* bu  = (const float*)d_in[8];
    const float* Wo  = (const float*)d_in[9];
    const float* bo  = (const float*)d_in[10];

    char* ws = (char*)d_ws;
    unsigned short* Bhi   = (unsigned short*)(ws);                    // 512 KB
    unsigned short* Blo   = (unsigned short*)(ws + (512ul<<10));      // 512 KB
    float* wcf            = (float*)(ws + (1ul<<20));                 // 4 KB
    float* ball           = (float*)(ws + (1ul<<20) + 4096);          // 4 KB
    float* convbuf        = (float*)(ws + (1ul<<20) + 8192);          // 512 KB
    float* gates          = (float*)(ws + (1ul<<20) + 8192 + (512ul<<10)); // 2 MB
    char*  after_g        = ws + (1ul<<20) + 8192 + (512ul<<10) + (2ul<<20);
    float* Pbuf           = (float*)(after_g);                        // 512 KB
    float* Sbuf           = (float*)(after_g + (512ul<<10));          // 512 KB
    unsigned int* qctr    = (unsigned int*)(after_g + (1ul<<20));     // 16 B
    unsigned int* qbuf    = (unsigned int*)(after_g + (1ul<<20) + 16); // 2 MB
    // provisional bit storage lives in d_out's head (16.8 MB), overwritten by out_k later
    unsigned long long* bits = (unsigned long long*)d_out;
    float* out = (float*)d_out;

    hipMemsetAsync(qctr, 0, 4, stream);
    hipLaunchKernelGGL(prep_wc_k,    dim3(4),    dim3(256), 0, stream, Wf, Wi, Wu, Wo,
                       bf, bi, bu, bo, wcf, ball);
    hipLaunchKernelGGL(prep_bfrag_k, dim3(128),  dim3(256), 0, stream, Wf, Wi, Wu, Wo, Bhi, Blo);
    hipLaunchKernelGGL(gates_k,      dim3(MM/MTILE), dim3(256), 0, stream,
                       x, Bhi, Blo, wcf, ball, convbuf, bits, qctr, qbuf);
    hipLaunchKernelGGL(fixup_k,      dim3(256),  dim3(256), 0, stream,
                       x, Wf, Wi, Wu, Wo, ball, convbuf, qctr, qbuf, bits);
    hipLaunchKernelGGL(finalize_k,   dim3(4096), dim3(256), 0, stream, bits, gates);
    hipLaunchKernelGGL(scan1_k,      dim3(4),    dim3(64),  0, stream, gates, Pbuf, Sbuf);
    hipLaunchKernelGGL(out_k,        dim3((MM*HH/4)/256), dim3(256), 0, stream,
                       gates, Pbuf, Sbuf, cx0, out);
}

// Round 9
// 976.387 us; speedup vs baseline: 2.2730x; 1.0407x over previous
//
#include <hip/hip_runtime.h>
#include <math.h>

#define TT 512
#define BB 256
#define DD 256
#define HH 256
#define QQ 256
#define MM (TT*BB)      // 131072 rows (t*B + b)
#define MTILE 32
#define WND 4e-4f       // proven in R7 with the same 3-product split
#define QCAP (1u<<19)
#define TCH 16
#define NCH (TT/TCH)    // 32 chunks

typedef float  f32x4  __attribute__((ext_vector_type(4)));
typedef short  bf16x8 __attribute__((ext_vector_type(8)));

__device__ __forceinline__ unsigned short bf16rn(float x){
    unsigned int u = __float_as_uint(x);
    unsigned int r = u + 0x7FFFu + ((u>>16)&1u);
    return (unsigned short)(r>>16);
}
__device__ __forceinline__ float bf2f(unsigned short h){
    return __uint_as_float(((unsigned int)h)<<16);
}

// ---- prep: per-n f32(conv-column-sum) and bias -------------------------------
__global__ __launch_bounds__(256)
void prep_wc_k(const float* __restrict__ Wf, const float* __restrict__ Wi,
               const float* __restrict__ Wu, const float* __restrict__ Wo,
               const float* __restrict__ bf, const float* __restrict__ bi,
               const float* __restrict__ bu, const float* __restrict__ bo,
               float* __restrict__ wcf, float* __restrict__ ball)
{
    int n = blockIdx.x * 256 + threadIdx.x;        // 1024
    int g = n >> 8, q = n & 255;
    const float* W    = (g==0) ? Wf : (g==1) ? Wi : (g==2) ? Wu : Wo;
    const float* bptr = (g==0) ? bf : (g==1) ? bi : (g==2) ? bu : bo;
    double s = 0.0;
    for (int j=0;j<256;j++) s += (double)W[q*512 + 256 + j];
    wcf[n] = (float)s; ball[n] = bptr[q];
}

// ---- prep: W -> bf16 hi/lo MFMA B-fragments (x-half k=0..255) ----------------
// B-frag 16x16x32: lane holds col=lane&15, k = kt*32 + (lane>>4)*8 + j.
__global__ __launch_bounds__(256)
void prep_bfrag_k(const float* __restrict__ Wf, const float* __restrict__ Wi,
                  const float* __restrict__ Wu, const float* __restrict__ Wo,
                  unsigned short* __restrict__ Bhi, unsigned short* __restrict__ Blo)
{
    int tau = blockIdx.x*256 + threadIdx.x;        // 32768 = 8kt * 64nt * 64lane
    int kt = tau >> 12, rest = tau & 4095;
    int nt = rest >> 6, lane = rest & 63;
    int col = nt*16 + (lane & 15);
    int g = col >> 8, q = col & 255;
    const float* W = (g==0) ? Wf : (g==1) ? Wi : (g==2) ? Wu : Wo;
    int k0 = kt*32 + (lane>>4)*8;
    unsigned int hp[4], lp[4];
    #pragma unroll
    for (int jj=0;jj<4;jj++){
        float w0 = W[q*512 + k0 + 2*jj];
        float w1 = W[q*512 + k0 + 2*jj + 1];
        unsigned short h0 = bf16rn(w0), h1 = bf16rn(w1);
        unsigned short l0 = bf16rn(w0 - bf2f(h0)), l1 = bf16rn(w1 - bf2f(h1));
        hp[jj] = (unsigned int)h0 | ((unsigned int)h1 << 16);
        lp[jj] = (unsigned int)l0 | ((unsigned int)l1 << 16);
    }
    *(uint4*)(Bhi + (size_t)tau*8) = make_uint4(hp[0],hp[1],hp[2],hp[3]);
    *(uint4*)(Blo + (size_t)tau*8) = make_uint4(lp[0],lp[1],lp[2],lp[3]);
}

// ---- main: conv + 3-product bf16-split MFMA (32 rows/wave) -------------------
__global__ __launch_bounds__(256, 2)
void gates_k(const float* __restrict__ x,
             const unsigned short* __restrict__ Bhi, const unsigned short* __restrict__ Blo,
             const float* __restrict__ wcf, const float* __restrict__ ball,
             float* __restrict__ convbuf,
             unsigned long long* __restrict__ bits,
             unsigned int* __restrict__ qctr, unsigned int* __restrict__ qbuf)
{
    __shared__ unsigned short Ahi[MTILE*DD];   // 16 KB, XOR-swizzled rows
    __shared__ unsigned short Alo[MTILE*DD];   // 16 KB
    __shared__ float convs[MTILE];
    const int tid = threadIdx.x;
    const int l   = tid & 63;
    const int w   = tid >> 6;                  // wave = gate id (0=f 1=i 2=u 3=o)
    const int m0  = blockIdx.x * MTILE;
    const unsigned long long ltm = (1ull<<l)-1ull;

    // stage x -> bf16 hi/lo LDS (+ conv per row); wave w stages rows 8w..8w+7
    const float4* xin = (const float4*)(x + (size_t)m0 * DD);
    #pragma unroll
    for (int i=0;i<8;i++){
        int row = 8*w + i;
        float4 v = xin[row*64 + l];
        int b0=v.x>0.f, b1=v.y>0.f, b2=v.z>0.f, b3=v.w>0.f;
        int p1=b0^b1, p2=p1^b2, p3=p2^b3;
        int s=b0+p1+p2+p3;
        unsigned long long mask=__ballot(p3);
        int X=(int)(__popcll(mask&ltm)&1);
        int contrib = X ? 4-s : s;
        #pragma unroll
        for(int off=1;off<64;off<<=1) contrib += __shfl_xor(contrib,off);
        if (l==0){ float cv=(float)contrib*(1.0f/DD); convs[row]=cv; convbuf[m0+row]=cv; }
        unsigned short h0=bf16rn(v.x), h1=bf16rn(v.y), h2=bf16rn(v.z), h3=bf16rn(v.w);
        unsigned short q0=bf16rn(v.x-bf2f(h0)), q1=bf16rn(v.y-bf2f(h1));
        unsigned short q2=bf16rn(v.z-bf2f(h2)), q3=bf16rn(v.w-bf2f(h3));
        uint2 hi2 = make_uint2((unsigned)h0|((unsigned)h1<<16), (unsigned)h2|((unsigned)h3<<16));
        uint2 lo2 = make_uint2((unsigned)q0|((unsigned)q1<<16), (unsigned)q2|((unsigned)q3<<16));
        int baddr = (row*512 + l*8) ^ ((row&7)<<4);
        *(uint2*)((char*)Ahi + baddr) = hi2;
        *(uint2*)((char*)Alo + baddr) = lo2;
    }
    __syncthreads();

    // MFMA: wave covers 32 rows (2 m-subtiles) x 256 cols of gate w, K=256
    f32x4 acc0[16], acc1[16];
    #pragma unroll
    for (int t=0;t<16;t++){ acc0[t]=(f32x4){0,0,0,0}; acc1[t]=(f32x4){0,0,0,0}; }

    const int r0  = l & 15;
    const int ks  = l >> 4;
    const int swz = (r0 & 7) << 4;

    #pragma unroll
    for (int kt=0; kt<8; kt++){
        int a0 = (r0*512 + ks*16 + kt*64) ^ swz;   // rows r0 (m2=0)
        int a1 = a0 + 16*512;                       // rows 16+r0 ((16+r)&7==r&7)
        bf16x8 ah0 = *(const bf16x8*)((const char*)Ahi + a0);
        bf16x8 al0 = *(const bf16x8*)((const char*)Alo + a0);
        bf16x8 ah1 = *(const bf16x8*)((const char*)Ahi + a1);
        bf16x8 al1 = *(const bf16x8*)((const char*)Alo + a1);
        const unsigned short* bh = Bhi + ((size_t)(kt*64 + 16*w)*64 + l)*8;
        const unsigned short* bl = Blo + ((size_t)(kt*64 + 16*w)*64 + l)*8;
        #pragma unroll
        for (int t=0;t<16;t++){
            bf16x8 vbh = *(const bf16x8*)(bh + (size_t)t*512);
            bf16x8 vbl = *(const bf16x8*)(bl + (size_t)t*512);
            acc0[t] = __builtin_amdgcn_mfma_f32_16x16x32_bf16(ah0, vbh, acc0[t], 0,0,0);
            acc0[t] = __builtin_amdgcn_mfma_f32_16x16x32_bf16(al0, vbh, acc0[t], 0,0,0);
            acc0[t] = __builtin_amdgcn_mfma_f32_16x16x32_bf16(ah0, vbl, acc0[t], 0,0,0);
            acc1[t] = __builtin_amdgcn_mfma_f32_16x16x32_bf16(ah1, vbh, acc1[t], 0,0,0);
            acc1[t] = __builtin_amdgcn_mfma_f32_16x16x32_bf16(al1, vbh, acc1[t], 0,0,0);
            acc1[t] = __builtin_amdgcn_mfma_f32_16x16x32_bf16(ah1, vbl, acc1[t], 0,0,0);
        }
    }

    // epilogue per m-subtile: provisional bit, packed word assembly, queue
    const int myu = l>>4, myj = l&3, mygrp = (l&15)>>2;

#define EPILOGUE(ACC, M2)                                                          \
    {                                                                              \
        unsigned long long word = 0;                                               \
        _Pragma("unroll")                                                          \
        for (int t=0;t<16;t++){                                                    \
            int n = w*256 + t*16 + (l&15);                                         \
            float wc = wcf[n], bb = ball[n];                                       \
            _Pragma("unroll")                                                      \
            for (int j=0;j<4;j++){                                                 \
                float cj = convs[(M2)*16 + myu*4 + j];                             \
                float rf = __fadd_rn(__fmaf_rn(cj, wc, ACC[t][j]), bb);            \
                int bit = rf > 0.5f;                                               \
                unsigned long long B = __ballot(bit != 0);                         \
                int cond = (j==myj) & ((t>>2)==myu);                               \
                unsigned long long chunk = (B >> (mygrp*16)) & 0xFFFFull;          \
                word |= cond ? (chunk << ((t&3)*16)) : 0ull;                       \
                bool win = fabsf(rf - 0.5f) < WND;                                 \
                unsigned long long wm = __ballot(win);                             \
                if (wm){                                                           \
                    int leader = (int)__ffsll(wm) - 1;                             \
                    unsigned int cnt = (unsigned int)__popcll(wm);                 \
                    unsigned int base = 0;                                         \
                    if (l == leader) base = atomicAdd(qctr, cnt);                  \
                    base = (unsigned int)__shfl((int)base, leader);                \
                    if (win){                                                      \
                        unsigned int pos = base + (unsigned int)__popcll(wm & ltm);\
                        if (pos < QCAP){                                           \
                            unsigned int mrow = (unsigned int)(m0 + (M2)*16 + myu*4 + j); \
                            qbuf[pos] = mrow | ((unsigned int)w<<17)               \
                                      | ((unsigned int)(t*16 + (l&15))<<19)        \
                                      | ((unsigned int)bit<<27);                   \
                        }                                                          \
                    }                                                              \
                }                                                                  \
            }                                                                      \
        }                                                                          \
        bits[((size_t)(m0 + (M2)*16 + r0)*4 + w)*4 + myu] = word;                  \
    }

    EPILOGUE(acc0, 0)
    EPILOGUE(acc1, 1)
#undef EPILOGUE
}

// ---- fixup: exact sequential-f32-FMA chain per queue item, patch bits --------
__global__ __launch_bounds__(256)
void fixup_k(const float* __restrict__ x,
             const float* __restrict__ Wf, const float* __restrict__ Wi,
             const float* __restrict__ Wu, const float* __restrict__ Wo,
             const float* __restrict__ ball, const float* __restrict__ convbuf,
             const unsigned int* __restrict__ qctr, const unsigned int* __restrict__ qbuf,
             unsigned long long* __restrict__ bits)
{
    unsigned int cnt = *qctr; if (cnt > QCAP) cnt = QCAP;
    unsigned int stride = gridDim.x * blockDim.x;
    for (unsigned int i = blockIdx.x*blockDim.x + threadIdx.x; i < cnt; i += stride){
        unsigned int it = qbuf[i];
        int m = it & 0x1FFFF;
        int g = (it>>17)&3;
        int q = (it>>19)&255;
        int prov = (it>>27)&1;
        const float* W = (g==0)?Wf:(g==1)?Wi:(g==2)?Wu:Wo;
        const float* wr = W + (size_t)q*512;
        const float* xr = x + (size_t)m*DD;
        float cv = convbuf[m];
        float a = 0.f;
        for (int k=0;k<DD;k++) a = __fmaf_rn(xr[k], wr[k], a);
        for (int k=0;k<DD;k++) a = __fmaf_rn(cv, wr[DD+k], a);
        float raw = __fadd_rn(a, ball[g*256+q]);
        int bit = raw > 0.5f;
        if (bit != prov)
            atomicXor(&bits[((size_t)m*4 + g)*4 + (q>>6)], 1ull<<(q&63));
    }
}

// ---- finalize: packed bits -> parity fraction -> gate value ------------------
__global__ __launch_bounds__(256)
void finalize_k(const unsigned long long* __restrict__ bits, float* __restrict__ gates)
{
    const int l = threadIdx.x & 63;
    const int wid = (int)((blockIdx.x*256 + threadIdx.x) >> 6);  // 16384 waves
    const unsigned long long ltm = (1ull<<l)-1ull;
    for (int it=0; it<32; it++){
        int R = wid*32 + it;                       // (m,gate) row, 0..524287
        unsigned long long wbits = bits[(size_t)R*4 + (l>>4)];
        int nib = (int)((wbits >> ((l&15)*4)) & 0xF);
        int b0=nib&1, b1=(nib>>1)&1, b2=(nib>>2)&1, b3=(nib>>3)&1;
        int p1=b0^b1, p2=p1^b2, p3=p2^b3;
        int s=b0+p1+p2+p3;
        unsigned long long mask=__ballot(p3);
        int X=(int)(__popcll(mask&ltm)&1);
        int contrib = X ? 4-s : s;
        #pragma unroll
        for(int off=1;off<64;off<<=1) contrib += __shfl_xor(contrib,off);
        if (l==0){
            int m = R>>2, g = R&3;
            float pf = (float)contrib*(1.0f/QQ);
            float val = (g==2) ? tanhf(pf) : 1.0f/(1.0f+expf(-pf));
            gates[(size_t)g*MM + m] = val;
        }
    }
}

// ---- scan A: per (b, chunk of 16 t): local P,S + chunk summary ---------------
__global__ __launch_bounds__(256)
void scanA_k(const float* __restrict__ gates, float* __restrict__ P,
             float* __restrict__ S, float* __restrict__ Psum, float* __restrict__ Ssum)
{
    int b  = threadIdx.x;          // 0..255
    int ch = blockIdx.x;           // 0..31
    const float* F = gates;
    const float* I = gates + MM;
    const float* G = gates + 2*(size_t)MM;
    float p = 1.f, s = 0.f;
    #pragma unroll
    for (int tt=0;tt<TCH;tt++){
        int m = (ch*TCH + tt)*BB + b;
        float f=F[m], i=I[m], g=G[m];
        s = f*s + i*g;
        p = p*f;
        P[m] = p; S[m] = s;
    }
    Psum[ch*BB + b] = p; Ssum[ch*BB + b] = s;
}

// ---- scan B: sequential combine of 32 chunk summaries per b ------------------
__global__ __launch_bounds__(256)
void scanB_k(const float* __restrict__ Psum, const float* __restrict__ Ssum,
             float* __restrict__ Ppre, float* __restrict__ Spre)
{
    int b = threadIdx.x;
    float cp = 1.f, cs = 0.f;
    for (int ch=0; ch<NCH; ch++){
        Ppre[ch*BB + b] = cp; Spre[ch*BB + b] = cs;
        float p = Psum[ch*BB + b], s = Ssum[ch*BB + b];
        cs = p*cs + s;
        cp = cp*p;
    }
}

// ---- broadcast: compose chunk prefix, c -> h ---------------------------------
__global__ __launch_bounds__(256)
void out_k(const float* __restrict__ gates, const float* __restrict__ P,
           const float* __restrict__ S, const float* __restrict__ Ppre,
           const float* __restrict__ Spre, const float* __restrict__ cx0,
           float* __restrict__ out)
{
    int idx = blockIdx.x * 256 + threadIdx.x;   // one float4 of h per thread
    int m  = idx >> 6;                          // wave-uniform row
    int h4 = (idx & 63) * 4;
    int b  = m & (BB-1);
    int ch = m >> 12;                           // t>>4
    const float* O = gates + 3*(size_t)MM;
    float p = P[m], s = S[m], o = O[m];
    float pp = Ppre[ch*BB + b], ss = Spre[ch*BB + b];
    float4 c0 = *(const float4*)&cx0[b*HH + h4];
    float4 c, hv;
    c.x = p*(pp*c0.x + ss) + s;
    c.y = p*(pp*c0.y + ss) + s;
    c.z = p*(pp*c0.z + ss) + s;
    c.w = p*(pp*c0.w + ss) + s;
    hv.x = o*tanhf(c.x);
    hv.y = o*tanhf(c.y);
    hv.z = o*tanhf(c.z);
    hv.w = o*tanhf(c.w);
    *(float4*)&out[(size_t)m * HH + h4] = hv;
    if (m >= (TT-1)*BB){                        // t == T-1: also emit hx, cx
        size_t base = (size_t)TT*BB*HH;
        *(float4*)&out[base + (size_t)b*HH + h4] = hv;
        *(float4*)&out[base + (size_t)BB*HH + (size_t)b*HH + h4] = c;
    }
}

extern "C" void kernel_launch(void* const* d_in, const int* in_sizes, int n_in,
                              void* d_out, int out_size, void* d_ws, size_t ws_size,
                              hipStream_t stream)
{
    const float* x   = (const float*)d_in[0];
    const float* cx0 = (const float*)d_in[2];
    const float* Wf  = (const float*)d_in[3];
    const float* bf  = (const float*)d_in[4];
    const float* Wi  = (const float*)d_in[5];
    const float* bi  = (const float*)d_in[6];
    const float* Wu  = (const float*)d_in[7];
    const float* bu  = (const float*)d_in[8];
    const float* Wo  = (const float*)d_in[9];
    const float* bo  = (const float*)d_in[10];

    char* ws = (char*)d_ws;
    unsigned short* Bhi = (unsigned short*)(ws);                  // 512 KB
    unsigned short* Blo = (unsigned short*)(ws + 0x080000);       // 512 KB
    float* wcf     = (float*)(ws + 0x100000);                     // 4 KB
    float* ball    = (float*)(ws + 0x101000);                     // 4 KB
    float* convbuf = (float*)(ws + 0x104000);                     // 512 KB
    float* gates   = (float*)(ws + 0x184000);                     // 2 MB
    float* Pbuf    = (float*)(ws + 0x384000);                     // 512 KB
    float* Sbuf    = (float*)(ws + 0x404000);                     // 512 KB
    float* Psum    = (float*)(ws + 0x484000);                     // 32 KB
    float* Ssum    = (float*)(ws + 0x48C000);                     // 32 KB
    float* Ppre    = (float*)(ws + 0x494000);                     // 32 KB
    float* Spre    = (float*)(ws + 0x49C000);                     // 32 KB
    unsigned int* qctr = (unsigned int*)(ws + 0x4A4000);          // 16 B
    unsigned int* qbuf = (unsigned int*)(ws + 0x4A4100);          // 2 MB
    // provisional bit storage in d_out's head (16.8 MB), overwritten by out_k later
    unsigned long long* bits = (unsigned long long*)d_out;
    float* out = (float*)d_out;

    hipMemsetAsync(qctr, 0, 4, stream);
    hipLaunchKernelGGL(prep_wc_k,    dim3(4),    dim3(256), 0, stream, Wf, Wi, Wu, Wo,
                       bf, bi, bu, bo, wcf, ball);
    hipLaunchKernelGGL(prep_bfrag_k, dim3(128),  dim3(256), 0, stream, Wf, Wi, Wu, Wo, Bhi, Blo);
    hipLaunchKernelGGL(gates_k,      dim3(MM/MTILE), dim3(256), 0, stream,
                       x, Bhi, Blo, wcf, ball, convbuf, bits, qctr, qbuf);
    hipLaunchKernelGGL(fixup_k,      dim3(1024), dim3(256), 0, stream,
                       x, Wf, Wi, Wu, Wo, ball, convbuf, qctr, qbuf, bits);
    hipLaunchKernelGGL(finalize_k,   dim3(4096), dim3(256), 0, stream, bits, gates);
    hipLaunchKernelGGL(scanA_k,      dim3(NCH),  dim3(256), 0, stream, gates, Pbuf, Sbuf, Psum, Ssum);
    hipLaunchKernelGGL(scanB_k,      dim3(1),    dim3(256), 0, stream, Psum, Ssum, Ppre, Spre);
    hipLaunchKernelGGL(out_k,        dim3((MM*HH/4)/256), dim3(256), 0, stream,
                       gates, Pbuf, Sbuf, Ppre, Spre, cx0, out);
}

// Round 10
// 922.569 us; speedup vs baseline: 2.4056x; 1.0583x over previous
//
#include <hip/hip_runtime.h>
#include <math.h>

#define TT 512
#define BB 256
#define DD 256
#define HH 256
#define QQ 256
#define MM (TT*BB)      // 131072 rows (t*B + b)
#define MTILE 32
#define WND 4e-4f       // proven R7/R9 with the 3-product split
#define QCAP (1u<<19)
#define TCH 16
#define NCH (TT/TCH)    // 32 chunks

typedef float  f32x4  __attribute__((ext_vector_type(4)));
typedef short  bf16x8 __attribute__((ext_vector_type(8)));

__device__ __forceinline__ unsigned short bf16rn(float x){
    unsigned int u = __float_as_uint(x);
    unsigned int r = u + 0x7FFFu + ((u>>16)&1u);
    return (unsigned short)(r>>16);
}
__device__ __forceinline__ float bf2f(unsigned short h){
    return __uint_as_float(((unsigned int)h)<<16);
}

// ---- prep: per-n f32(conv-column-sum) and bias -------------------------------
__global__ __launch_bounds__(256)
void prep_wc_k(const float* __restrict__ Wf, const float* __restrict__ Wi,
               const float* __restrict__ Wu, const float* __restrict__ Wo,
               const float* __restrict__ bf, const float* __restrict__ bi,
               const float* __restrict__ bu, const float* __restrict__ bo,
               float* __restrict__ wcf, float* __restrict__ ball)
{
    int n = blockIdx.x * 256 + threadIdx.x;        // 1024
    int g = n >> 8, q = n & 255;
    const float* W    = (g==0) ? Wf : (g==1) ? Wi : (g==2) ? Wu : Wo;
    const float* bptr = (g==0) ? bf : (g==1) ? bi : (g==2) ? bu : bo;
    double s = 0.0;
    for (int j=0;j<256;j++) s += (double)W[q*512 + 256 + j];
    wcf[n] = (float)s; ball[n] = bptr[q];
}

// ---- prep: W -> bf16 hi/lo MFMA B-fragments (x-half k=0..255) ----------------
// B-frag 16x16x32: lane holds col=lane&15, k = kt*32 + (lane>>4)*8 + j.
__global__ __launch_bounds__(256)
void prep_bfrag_k(const float* __restrict__ Wf, const float* __restrict__ Wi,
                  const float* __restrict__ Wu, const float* __restrict__ Wo,
                  unsigned short* __restrict__ Bhi, unsigned short* __restrict__ Blo)
{
    int tau = blockIdx.x*256 + threadIdx.x;        // 32768 = 8kt * 64nt * 64lane
    int kt = tau >> 12, rest = tau & 4095;
    int nt = rest >> 6, lane = rest & 63;
    int col = nt*16 + (lane & 15);
    int g = col >> 8, q = col & 255;
    const float* W = (g==0) ? Wf : (g==1) ? Wi : (g==2) ? Wu : Wo;
    int k0 = kt*32 + (lane>>4)*8;
    unsigned int hp[4], lp[4];
    #pragma unroll
    for (int jj=0;jj<4;jj++){
        float w0 = W[q*512 + k0 + 2*jj];
        float w1 = W[q*512 + k0 + 2*jj + 1];
        unsigned short h0 = bf16rn(w0), h1 = bf16rn(w1);
        unsigned short l0 = bf16rn(w0 - bf2f(h0)), l1 = bf16rn(w1 - bf2f(h1));
        hp[jj] = (unsigned int)h0 | ((unsigned int)h1 << 16);
        lp[jj] = (unsigned int)l0 | ((unsigned int)l1 << 16);
    }
    *(uint4*)(Bhi + (size_t)tau*8) = make_uint4(hp[0],hp[1],hp[2],hp[3]);
    *(uint4*)(Blo + (size_t)tau*8) = make_uint4(lp[0],lp[1],lp[2],lp[3]);
}

// ---- main: conv + 3-product bf16-split MFMA ----------------------------------
// Grid: 8192 blocks = 4096 m-tiles x 2 gate-pairs. Block: 512 thr = 8 waves.
// Wave w: gate g = gp*2 + (w>>2), n-quarter qn = w&3 (4 t-tiles), 2 m-subtiles.
// Per wave/kt: 8 global B loads + 4 A ds_reads -> 24 MFMAs, acc = 32 f32.
__global__ __launch_bounds__(512, 4)
void gates_k(const float* __restrict__ x,
             const unsigned short* __restrict__ Bhi, const unsigned short* __restrict__ Blo,
             const float* __restrict__ wcf, const float* __restrict__ ball,
             float* __restrict__ convbuf,
             unsigned long long* __restrict__ bits,
             unsigned int* __restrict__ qctr, unsigned int* __restrict__ qbuf)
{
    __shared__ unsigned short Ahi[MTILE*DD];   // 16 KB, XOR-swizzled rows
    __shared__ unsigned short Alo[MTILE*DD];   // 16 KB
    __shared__ float convs[MTILE];
    const int tid = threadIdx.x;
    const int l   = tid & 63;
    const int w   = tid >> 6;                  // 0..7
    const int gp  = blockIdx.x & 1;            // gate pair
    const int m0  = (blockIdx.x >> 1) * MTILE;
    const int g   = gp*2 + (w>>2);             // gate 0..3
    const int qn  = w & 3;                     // n-quarter (64 cols)
    const unsigned long long ltm = (1ull<<l)-1ull;

    // stage x -> bf16 hi/lo LDS (+ conv per row); wave w stages rows 4w..4w+3
    const float4* xin = (const float4*)(x + (size_t)m0 * DD);
    #pragma unroll
    for (int i=0;i<4;i++){
        int row = 4*w + i;
        float4 v = xin[row*64 + l];
        int b0=v.x>0.f, b1=v.y>0.f, b2=v.z>0.f, b3=v.w>0.f;
        int p1=b0^b1, p2=p1^b2, p3=p2^b3;
        int s=b0+p1+p2+p3;
        unsigned long long mask=__ballot(p3);
        int X=(int)(__popcll(mask&ltm)&1);
        int contrib = X ? 4-s : s;
        #pragma unroll
        for(int off=1;off<64;off<<=1) contrib += __shfl_xor(contrib,off);
        if (l==0){ float cv=(float)contrib*(1.0f/DD); convs[row]=cv; convbuf[m0+row]=cv; }
        unsigned short h0=bf16rn(v.x), h1=bf16rn(v.y), h2=bf16rn(v.z), h3=bf16rn(v.w);
        unsigned short q0=bf16rn(v.x-bf2f(h0)), q1=bf16rn(v.y-bf2f(h1));
        unsigned short q2=bf16rn(v.z-bf2f(h2)), q3=bf16rn(v.w-bf2f(h3));
        uint2 hi2 = make_uint2((unsigned)h0|((unsigned)h1<<16), (unsigned)h2|((unsigned)h3<<16));
        uint2 lo2 = make_uint2((unsigned)q0|((unsigned)q1<<16), (unsigned)q2|((unsigned)q3<<16));
        int baddr = (row*512 + l*8) ^ ((row&7)<<4);
        *(uint2*)((char*)Ahi + baddr) = hi2;
        *(uint2*)((char*)Alo + baddr) = lo2;
    }
    __syncthreads();

    // MFMA: wave covers 32 rows (2 m-subtiles) x 64 cols (4 t-tiles) of gate g
    f32x4 acc0[4], acc1[4];
    #pragma unroll
    for (int t=0;t<4;t++){ acc0[t]=(f32x4){0,0,0,0}; acc1[t]=(f32x4){0,0,0,0}; }

    const int r0  = l & 15;
    const int ks  = l >> 4;
    const int swz = (r0 & 7) << 4;

    #pragma unroll
    for (int kt=0; kt<8; kt++){
        int a0 = (r0*512 + ks*16 + kt*64) ^ swz;   // subtile 0
        int a1 = a0 + 16*512;                       // subtile 1 ((16+r)&7==r&7)
        bf16x8 ah0 = *(const bf16x8*)((const char*)Ahi + a0);
        bf16x8 al0 = *(const bf16x8*)((const char*)Alo + a0);
        bf16x8 ah1 = *(const bf16x8*)((const char*)Ahi + a1);
        bf16x8 al1 = *(const bf16x8*)((const char*)Alo + a1);
        const unsigned short* bh = Bhi + ((size_t)(kt*64 + g*16 + qn*4)*64 + l)*8;
        const unsigned short* bl = Blo + ((size_t)(kt*64 + g*16 + qn*4)*64 + l)*8;
        #pragma unroll
        for (int t=0;t<4;t++){
            bf16x8 vbh = *(const bf16x8*)(bh + (size_t)t*512);
            bf16x8 vbl = *(const bf16x8*)(bl + (size_t)t*512);
            acc0[t] = __builtin_amdgcn_mfma_f32_16x16x32_bf16(ah0, vbh, acc0[t], 0,0,0);
            acc0[t] = __builtin_amdgcn_mfma_f32_16x16x32_bf16(al0, vbh, acc0[t], 0,0,0);
            acc0[t] = __builtin_amdgcn_mfma_f32_16x16x32_bf16(ah0, vbl, acc0[t], 0,0,0);
            acc1[t] = __builtin_amdgcn_mfma_f32_16x16x32_bf16(ah1, vbh, acc1[t], 0,0,0);
            acc1[t] = __builtin_amdgcn_mfma_f32_16x16x32_bf16(al1, vbh, acc1[t], 0,0,0);
            acc1[t] = __builtin_amdgcn_mfma_f32_16x16x32_bf16(ah1, vbl, acc1[t], 0,0,0);
        }
    }

    // epilogue per m-subtile: one u64 word (this wave's 64 cols) per row.
    // acc element at lane l, reg j = C[row=(l>>4)*4+j][col=t*16+(l&15)].
    const int myj = l & 3, mygrp = r0 >> 2;

#define EPILOGUE(ACC, M2)                                                          \
    {                                                                              \
        unsigned long long word = 0;                                               \
        _Pragma("unroll")                                                          \
        for (int t=0;t<4;t++){                                                     \
            int n = g*256 + (qn*4 + t)*16 + r0;                                    \
            float wc = wcf[n], bb = ball[n];                                       \
            _Pragma("unroll")                                                      \
            for (int j=0;j<4;j++){                                                 \
                float cj = convs[(M2)*16 + ks*4 + j];                              \
                float rf = __fadd_rn(__fmaf_rn(cj, wc, ACC[t][j]), bb);            \
                int bit = rf > 0.5f;                                               \
                unsigned long long B = __ballot(bit != 0);                         \
                unsigned long long chunk = (B >> (mygrp*16)) & 0xFFFFull;          \
                word |= (j==myj) ? (chunk << (t*16)) : 0ull;                       \
                bool win = fabsf(rf - 0.5f) < WND;                                 \
                unsigned long long wm = __ballot(win);                             \
                if (wm){                                                           \
                    int leader = (int)__ffsll(wm) - 1;                             \
                    unsigned int cnt = (unsigned int)__popcll(wm);                 \
                    unsigned int base = 0;                                         \
                    if (l == leader) base = atomicAdd(qctr, cnt);                  \
                    base = (unsigned int)__shfl((int)base, leader);                \
                    if (win){                                                      \
                        unsigned int pos = base + (unsigned int)__popcll(wm & ltm);\
                        if (pos < QCAP){                                           \
                            unsigned int mrow = (unsigned int)(m0 + (M2)*16 + ks*4 + j); \
                            qbuf[pos] = mrow | ((unsigned int)g<<17)               \
                                      | ((unsigned int)((qn*4+t)*16 + r0)<<19)     \
                                      | ((unsigned int)bit<<27);                   \
                        }                                                          \
                    }                                                              \
                }                                                                  \
            }                                                                      \
        }                                                                          \
        if (l < 16)                                                                \
            bits[((size_t)(m0 + (M2)*16 + r0)*4 + g)*4 + qn] = word;               \
    }

    EPILOGUE(acc0, 0)
    EPILOGUE(acc1, 1)
#undef EPILOGUE
}

// ---- fixup: exact sequential-f32-FMA chain per queue item, patch bits --------
__global__ __launch_bounds__(256)
void fixup_k(const float* __restrict__ x,
             const float* __restrict__ Wf, const float* __restrict__ Wi,
             const float* __restrict__ Wu, const float* __restrict__ Wo,
             const float* __restrict__ ball, const float* __restrict__ convbuf,
             const unsigned int* __restrict__ qctr, const unsigned int* __restrict__ qbuf,
             unsigned long long* __restrict__ bits)
{
    unsigned int cnt = *qctr; if (cnt > QCAP) cnt = QCAP;
    unsigned int stride = gridDim.x * blockDim.x;
    for (unsigned int i = blockIdx.x*blockDim.x + threadIdx.x; i < cnt; i += stride){
        unsigned int it = qbuf[i];
        int m = it & 0x1FFFF;
        int g = (it>>17)&3;
        int q = (it>>19)&255;
        int prov = (it>>27)&1;
        const float* W = (g==0)?Wf:(g==1)?Wi:(g==2)?Wu:Wo;
        const float* wr = W + (size_t)q*512;
        const float* xr = x + (size_t)m*DD;
        float cv = convbuf[m];
        float a = 0.f;
        for (int k=0;k<DD;k++) a = __fmaf_rn(xr[k], wr[k], a);
        for (int k=0;k<DD;k++) a = __fmaf_rn(cv, wr[DD+k], a);
        float raw = __fadd_rn(a, ball[g*256+q]);
        int bit = raw > 0.5f;
        if (bit != prov)
            atomicXor(&bits[((size_t)m*4 + g)*4 + (q>>6)], 1ull<<(q&63));
    }
}

// ---- finalize: packed bits -> parity fraction -> gate value ------------------
__global__ __launch_bounds__(256)
void finalize_k(const unsigned long long* __restrict__ bits, float* __restrict__ gates)
{
    const int l = threadIdx.x & 63;
    const int wid = (int)((blockIdx.x*256 + threadIdx.x) >> 6);  // 16384 waves
    const unsigned long long ltm = (1ull<<l)-1ull;
    for (int it=0; it<32; it++){
        int R = wid*32 + it;                       // (m,gate) row, 0..524287
        unsigned long long wbits = bits[(size_t)R*4 + (l>>4)];
        int nib = (int)((wbits >> ((l&15)*4)) & 0xF);
        int b0=nib&1, b1=(nib>>1)&1, b2=(nib>>2)&1, b3=(nib>>3)&1;
        int p1=b0^b1, p2=p1^b2, p3=p2^b3;
        int s=b0+p1+p2+p3;
        unsigned long long mask=__ballot(p3);
        int X=(int)(__popcll(mask&ltm)&1);
        int contrib = X ? 4-s : s;
        #pragma unroll
        for(int off=1;off<64;off<<=1) contrib += __shfl_xor(contrib,off);
        if (l==0){
            int m = R>>2, g = R&3;
            float pf = (float)contrib*(1.0f/QQ);
            float val = (g==2) ? tanhf(pf) : 1.0f/(1.0f+expf(-pf));
            gates[(size_t)g*MM + m] = val;
        }
    }
}

// ---- scan A: per (b, chunk of 16 t): local P,S + chunk summary ---------------
__global__ __launch_bounds__(256)
void scanA_k(const float* __restrict__ gates, float* __restrict__ P,
             float* __restrict__ S, float* __restrict__ Psum, float* __restrict__ Ssum)
{
    int b  = threadIdx.x;          // 0..255
    int ch = blockIdx.x;           // 0..31
    const float* F = gates;
    const float* I = gates + MM;
    const float* G = gates + 2*(size_t)MM;
    float p = 1.f, s = 0.f;
    #pragma unroll
    for (int tt=0;tt<TCH;tt++){
        int m = (ch*TCH + tt)*BB + b;
        float f=F[m], i=I[m], g=G[m];
        s = f*s + i*g;
        p = p*f;
        P[m] = p; S[m] = s;
    }
    Psum[ch*BB + b] = p; Ssum[ch*BB + b] = s;
}

// ---- scan B: sequential combine of 32 chunk summaries per b ------------------
__global__ __launch_bounds__(256)
void scanB_k(const float* __restrict__ Psum, const float* __restrict__ Ssum,
             float* __restrict__ Ppre, float* __restrict__ Spre)
{
    int b = threadIdx.x;
    float cp = 1.f, cs = 0.f;
    for (int ch=0; ch<NCH; ch++){
        Ppre[ch*BB + b] = cp; Spre[ch*BB + b] = cs;
        float p = Psum[ch*BB + b], s = Ssum[ch*BB + b];
        cs = p*cs + s;
        cp = cp*p;
    }
}

// ---- broadcast: compose chunk prefix, c -> h ---------------------------------
__global__ __launch_bounds__(256)
void out_k(const float* __restrict__ gates, const float* __restrict__ P,
           const float* __restrict__ S, const float* __restrict__ Ppre,
           const float* __restrict__ Spre, const float* __restrict__ cx0,
           float* __restrict__ out)
{
    int idx = blockIdx.x * 256 + threadIdx.x;   // one float4 of h per thread
    int m  = idx >> 6;                          // wave-uniform row
    int h4 = (idx & 63) * 4;
    int b  = m & (BB-1);
    int ch = m >> 12;                           // t>>4
    const float* O = gates + 3*(size_t)MM;
    float p = P[m], s = S[m], o = O[m];
    float pp = Ppre[ch*BB + b], ss = Spre[ch*BB + b];
    float4 c0 = *(const float4*)&cx0[b*HH + h4];
    float4 c, hv;
    c.x = p*(pp*c0.x + ss) + s;
    c.y = p*(pp*c0.y + ss) + s;
    c.z = p*(pp*c0.z + ss) + s;
    c.w = p*(pp*c0.w + ss) + s;
    hv.x = o*tanhf(c.x);
    hv.y = o*tanhf(c.y);
    hv.z = o*tanhf(c.z);
    hv.w = o*tanhf(c.w);
    *(float4*)&out[(size_t)m * HH + h4] = hv;
    if (m >= (TT-1)*BB){                        // t == T-1: also emit hx, cx
        size_t base = (size_t)TT*BB*HH;
        *(float4*)&out[base + (size_t)b*HH + h4] = hv;
        *(float4*)&out[base + (size_t)BB*HH + (size_t)b*HH + h4] = c;
    }
}

extern "C" void kernel_launch(void* const* d_in, const int* in_sizes, int n_in,
                              void* d_out, int out_size, void* d_ws, size_t ws_size,
                              hipStream_t stream)
{
    const float* x   = (const float*)d_in[0];
    const float* cx0 = (const float*)d_in[2];
    const float* Wf  = (const float*)d_in[3];
    const float* bf  = (const float*)d_in[4];
    const float* Wi  = (const float*)d_in[5];
    const float* bi  = (const float*)d_in[6];
    const float* Wu  = (const float*)d_in[7];
    const float* bu  = (const float*)d_in[8];
    const float* Wo  = (const float*)d_in[9];
    const float* bo  = (const float*)d_in[10];

    char* ws = (char*)d_ws;
    unsigned short* Bhi = (unsigned short*)(ws);                  // 512 KB
    unsigned short* Blo = (unsigned short*)(ws + 0x080000);       // 512 KB
    float* wcf     = (float*)(ws + 0x100000);                     // 4 KB
    float* ball    = (float*)(ws + 0x101000);                     // 4 KB
    float* convbuf = (float*)(ws + 0x104000);                     // 512 KB
    float* gates   = (float*)(ws + 0x184000);                     // 2 MB
    float* Pbuf    = (float*)(ws + 0x384000);                     // 512 KB
    float* Sbuf    = (float*)(ws + 0x404000);                     // 512 KB
    float* Psum    = (float*)(ws + 0x484000);                     // 32 KB
    float* Ssum    = (float*)(ws + 0x48C000);                     // 32 KB
    float* Ppre    = (float*)(ws + 0x494000);                     // 32 KB
    float* Spre    = (float*)(ws + 0x49C000);                     // 32 KB
    unsigned int* qctr = (unsigned int*)(ws + 0x4A4000);          // 16 B
    unsigned int* qbuf = (unsigned int*)(ws + 0x4A4100);          // 2 MB
    // provisional bit storage in d_out's head (16.8 MB), overwritten by out_k later
    unsigned long long* bits = (unsigned long long*)d_out;
    float* out = (float*)d_out;

    hipMemsetAsync(qctr, 0, 4, stream);
    hipLaunchKernelGGL(prep_wc_k,    dim3(4),    dim3(256), 0, stream, Wf, Wi, Wu, Wo,
                       bf, bi, bu, bo, wcf, ball);
    hipLaunchKernelGGL(prep_bfrag_k, dim3(128),  dim3(256), 0, stream, Wf, Wi, Wu, Wo, Bhi, Blo);
    hipLaunchKernelGGL(gates_k,      dim3((MM/MTILE)*2), dim3(512), 0, stream,
                       x, Bhi, Blo, wcf, ball, convbuf, bits, qctr, qbuf);
    hipLaunchKernelGGL(fixup_k,      dim3(1024), dim3(256), 0, stream,
                       x, Wf, Wi, Wu, Wo, ball, convbuf, qctr, qbuf, bits);
    hipLaunchKernelGGL(finalize_k,   dim3(4096), dim3(256), 0, stream, bits, gates);
    hipLaunchKernelGGL(scanA_k,      dim3(NCH),  dim3(256), 0, stream, gates, Pbuf, Sbuf, Psum, Ssum);
    hipLaunchKernelGGL(scanB_k,      dim3(1),    dim3(256), 0, stream, Psum, Ssum, Ppre, Spre);
    hipLaunchKernelGGL(out_k,        dim3((MM*HH/4)/256), dim3(256), 0, stream,
                       gates, Pbuf, Sbuf, Ppre, Spre, cx0, out);
}